// Round 3
// baseline (2331.064 us; speedup 1.0000x reference)
//
#include <hip/hip_runtime.h>
#include <cstdint>

// RNN: out[t,b,h] = tanh(x[b,t,:]@Wx + bx + h_{t-1}@Wh + bh), h_0 = h0.
#define BB 128
#define LL 1024
#define II 256
#define HH 512

typedef _Float16 f16;
typedef _Float16 f16x2 __attribute__((ext_vector_type(2)));
typedef _Float16 f16x4 __attribute__((ext_vector_type(4)));
typedef _Float16 f16x8 __attribute__((ext_vector_type(8)));
typedef float f32x4 __attribute__((ext_vector_type(4)));

// ---------------- Phase 1: xp[t,b,:] = x[b,t,:] @ Wx + bx  (written to out) --
// Unchanged from R2 (works, ~290us). Optimization target for a later round.
__global__ __launch_bounds__(256, 4) void xproj_gemm(
    const float* __restrict__ x, const float* __restrict__ Wx,
    const float* __restrict__ bx, float* __restrict__ out) {
  const int t0 = blockIdx.x;        // time index
  const int n0 = blockIdx.y * 128;  // output-column tile
  __shared__ f16 As[128][72];
  __shared__ f16 Bs[128][72];       // TRANSPOSED: [col][k]
  const int tid  = threadIdx.x;
  const int lane = tid & 63;
  const int wid  = tid >> 6;
  const int wr   = wid >> 1, wc = wid & 1;

  f32x4 acc[4][4];
#pragma unroll
  for (int mi = 0; mi < 4; ++mi)
#pragma unroll
    for (int ni = 0; ni < 4; ++ni) acc[mi][ni] = f32x4{0.f, 0.f, 0.f, 0.f};

  for (int kt = 0; kt < 4; ++kt) {
    const int k0 = kt * 64;
#pragma unroll
    for (int rep = 0; rep < 8; ++rep) {
      const int idx = rep * 256 + tid;
      const int row = idx >> 4;
      const int c4  = idx & 15;
      const float4 v =
          *(reinterpret_cast<const float4*>(x + ((size_t)row * LL + t0) * II + k0) + c4);
      f16x4 p = {(f16)v.x, (f16)v.y, (f16)v.z, (f16)v.w};
      *reinterpret_cast<f16x4*>(&As[row][c4 * 4]) = p;
    }
    {
      const int c  = tid & 127;
      const int kh = tid >> 7;
      const float* wp = Wx + (size_t)(k0 + kh * 32) * HH + n0 + c;
#pragma unroll
      for (int m8 = 0; m8 < 4; ++m8) {
        f16x8 pk;
#pragma unroll
        for (int j = 0; j < 8; ++j) pk[j] = (f16)wp[(size_t)(m8 * 8 + j) * HH];
        *reinterpret_cast<f16x8*>(&Bs[c][kh * 32 + m8 * 8]) = pk;
      }
    }
    __syncthreads();
#pragma unroll
    for (int kk2 = 0; kk2 < 2; ++kk2) {
      const int kf = kk2 * 32 + ((lane >> 4) << 3);
      f16x8 af[4], bf[4];
#pragma unroll
      for (int mi = 0; mi < 4; ++mi)
        af[mi] = *reinterpret_cast<const f16x8*>(&As[wr * 64 + mi * 16 + (lane & 15)][kf]);
#pragma unroll
      for (int ni = 0; ni < 4; ++ni)
        bf[ni] = *reinterpret_cast<const f16x8*>(&Bs[wc * 64 + ni * 16 + (lane & 15)][kf]);
#pragma unroll
      for (int mi = 0; mi < 4; ++mi)
#pragma unroll
        for (int ni = 0; ni < 4; ++ni)
          acc[mi][ni] =
              __builtin_amdgcn_mfma_f32_16x16x32_f16(af[mi], bf[ni], acc[mi][ni], 0, 0, 0);
    }
    __syncthreads();
  }
#pragma unroll
  for (int mi = 0; mi < 4; ++mi) {
    const int row = wr * 64 + mi * 16 + ((lane >> 4) << 2);
#pragma unroll
    for (int ni = 0; ni < 4; ++ni) {
      const int col = n0 + wc * 64 + ni * 16 + (lane & 15);
      const float bxi = bx[col];
#pragma unroll
      for (int q = 0; q < 4; ++q)
        out[((size_t)t0 * BB + (row + q)) * HH + col] = acc[mi][ni][q] + bxi;
    }
  }
}

// ---------------- Phase 2: persistent per-row scan (v2) ----------------------
// 128 blocks x 512 threads (8 waves = 2/SIMD -> 256-VGPR budget, pinned by
// amdgpu_waves_per_eu(2,2) so the allocator cannot chase occupancy and spill).
// Thread (kq, c0) owns 4 output columns over one K-quarter: 64 k-pairs x 4
// cols = 256 packed-f16 weight dwords: 208 in VGPRs, 48 streamed from LDS
// (98 KB/step, under the ~85 B/cy ds_read_b128 ceiling). h broadcast via
// wave-uniform uint4 LDS reads (16/thread/step). 4-way k-reduction via LDS.
#define RP 52                     // register-resident k-pairs (of 64)
#define WSTRIDE 64                // padded dwords per thread in wlds
#define SMEM_BYTES (131072 + 1024 + 1024 + 8192)

__device__ __forceinline__ float fdot2(uint32_t w, uint32_t h, float acc) {
#if __has_builtin(__builtin_amdgcn_fdot2)
  return __builtin_amdgcn_fdot2(__builtin_bit_cast(f16x2, w),
                                __builtin_bit_cast(f16x2, h), acc, false);
#else
  asm("v_dot2_f32_f16 %0, %1, %2, %0" : "+v"(acc) : "v"(w), "v"(h));
  return acc;
#endif
}

__device__ __forceinline__ float fast_tanh(float s) {
  // tanh(s) = 1 - 2/(exp2(s*2*log2 e)+1); exact at +-inf, ~1e-6 rel err.
  const float z = 2.885390081777927f * s;
#if __has_builtin(__builtin_amdgcn_exp2f)
  const float e = __builtin_amdgcn_exp2f(z);
#else
  const float e = __builtin_exp2f(z);
#endif
#if __has_builtin(__builtin_amdgcn_rcpf)
  return 1.f - 2.f * __builtin_amdgcn_rcpf(e + 1.f);
#else
  return 1.f - 2.f / (e + 1.f);
#endif
}

__global__ __launch_bounds__(512)
__attribute__((amdgpu_waves_per_eu(2, 2)))
void rnn_scan(const float* __restrict__ Wh, const float* __restrict__ bh,
              const float* __restrict__ h0, float* __restrict__ out) {
  extern __shared__ unsigned char smem[];
  uint32_t* wlds = reinterpret_cast<uint32_t*>(smem);            // 512*64 dw
  uint32_t* hA   = reinterpret_cast<uint32_t*>(smem + 131072);   // 256 dw
  uint32_t* hB   = reinterpret_cast<uint32_t*>(smem + 132096);   // 256 dw
  float*    red  = reinterpret_cast<float*>(smem + 133120);      // [4][512]

  const int r   = blockIdx.x;
  const int tid = threadIdx.x;
  const int kq  = tid >> 7;          // k-quarter
  const int c0  = (tid & 127) * 4;   // first of 4 owned columns
  const int kb  = kq * 128;
  const int sw  = (tid & 7) << 2;    // b128 bank-quad spread

  // ---- Preload Wh: pack (k,k+1) f16 pairs per column. 208 reg + 48 LDS. ----
  uint32_t wreg[4 * RP];
#pragma unroll
  for (int p = 0; p < 64; ++p) {
    const float4 r0 = *reinterpret_cast<const float4*>(Wh + (size_t)(kb + 2 * p) * HH + c0);
    const float4 r1 = *reinterpret_cast<const float4*>(Wh + (size_t)(kb + 2 * p + 1) * HH + c0);
    f16x2 q0 = {(f16)r0.x, (f16)r1.x};
    f16x2 q1 = {(f16)r0.y, (f16)r1.y};
    f16x2 q2 = {(f16)r0.z, (f16)r1.z};
    f16x2 q3 = {(f16)r0.w, (f16)r1.w};
    const uint32_t d0 = __builtin_bit_cast(uint32_t, q0);
    const uint32_t d1 = __builtin_bit_cast(uint32_t, q1);
    const uint32_t d2 = __builtin_bit_cast(uint32_t, q2);
    const uint32_t d3 = __builtin_bit_cast(uint32_t, q3);
    if (p < RP) {
      wreg[4 * p + 0] = d0; wreg[4 * p + 1] = d1;
      wreg[4 * p + 2] = d2; wreg[4 * p + 3] = d3;
    } else {
      uint4 w4 = {d0, d1, d2, d3};
      *reinterpret_cast<uint4*>(wlds + tid * WSTRIDE + ((4 * (p - RP)) ^ sw)) = w4;
    }
  }
  const float bh_r = bh[tid];
  if (tid < 256) {
    f16x2 hp = {(f16)h0[(size_t)r * HH + 2 * tid], (f16)h0[(size_t)r * HH + 2 * tid + 1]};
    hA[tid] = __builtin_bit_cast(uint32_t, hp);
  }
  float* orow = out + (size_t)r * HH;
  float xpv = orow[tid];  // xp(t=0) was written here by phase 1
  __syncthreads();

  uint32_t* hcur = hA;
  uint32_t* hnxt = hB;
#pragma unroll 1
  for (int t = 0; t < LL; ++t) {
    // Prefetch next step's xp early; latency hides under the dot2 block.
    const int tn = (t + 1 < LL) ? t + 1 : LL - 1;
    const float xpv_n = orow[(size_t)tn * (BB * HH) + tid];

    float a0 = 0.f, a1 = 0.f, a2 = 0.f, a3 = 0.f;
    const uint4* hc4 = reinterpret_cast<const uint4*>(hcur) + kq * 16;
#pragma unroll
    for (int u = 0; u < 13; ++u) {  // pairs 0..51: register weights
      const uint4 hv = hc4[u];
      const uint32_t hs[4] = {hv.x, hv.y, hv.z, hv.w};
#pragma unroll
      for (int e = 0; e < 4; ++e) {
        const int p = 4 * u + e;
        a0 = fdot2(wreg[4 * p + 0], hs[e], a0);
        a1 = fdot2(wreg[4 * p + 1], hs[e], a1);
        a2 = fdot2(wreg[4 * p + 2], hs[e], a2);
        a3 = fdot2(wreg[4 * p + 3], hs[e], a3);
      }
    }
#pragma unroll
    for (int u = 13; u < 16; ++u) {  // pairs 52..63: LDS-streamed weights
      const uint4 hv = hc4[u];
      const uint32_t hs[4] = {hv.x, hv.y, hv.z, hv.w};
#pragma unroll
      for (int e = 0; e < 4; ++e) {
        const int p = 4 * u + e;
        const uint4 wv =
            *reinterpret_cast<const uint4*>(wlds + tid * WSTRIDE + ((4 * (p - RP)) ^ sw));
        a0 = fdot2(wv.x, hs[e], a0);
        a1 = fdot2(wv.y, hs[e], a1);
        a2 = fdot2(wv.z, hs[e], a2);
        a3 = fdot2(wv.w, hs[e], a3);
      }
    }
    *reinterpret_cast<f32x4*>(red + kq * HH + c0) = f32x4{a0, a1, a2, a3};
    __syncthreads();

    // Column tid: combine 4 k-quarter partials, add xp + bh, tanh, emit.
    const float s =
        red[tid] + red[HH + tid] + red[2 * HH + tid] + red[3 * HH + tid] + xpv + bh_r;
    const float h = fast_tanh(s);
    orow[(size_t)t * (BB * HH) + tid] = h;
    const float hn = __shfl_down(h, 1, 64);
    if (!(tid & 1)) {
      f16x2 hp2 = {(f16)h, (f16)hn};
      hnxt[tid >> 1] = __builtin_bit_cast(uint32_t, hp2);
    }
    __syncthreads();

    uint32_t* tmp = hcur; hcur = hnxt; hnxt = tmp;
    xpv = xpv_n;
  }
}

extern "C" void kernel_launch(void* const* d_in, const int* in_sizes, int n_in,
                              void* d_out, int out_size, void* d_ws, size_t ws_size,
                              hipStream_t stream) {
  const float* x  = (const float*)d_in[0];
  const float* h0 = (const float*)d_in[1];
  const float* Wx = (const float*)d_in[2];
  const float* bx = (const float*)d_in[3];
  const float* Wh = (const float*)d_in[4];
  const float* bh = (const float*)d_in[5];
  float* out = (float*)d_out;

  (void)in_sizes; (void)n_in; (void)out_size; (void)d_ws; (void)ws_size;

  hipFuncSetAttribute(reinterpret_cast<const void*>(rnn_scan),
                      hipFuncAttributeMaxDynamicSharedMemorySize, SMEM_BYTES);

  xproj_gemm<<<dim3(LL, HH / 128), 256, 0, stream>>>(x, Wx, bx, out);
  rnn_scan<<<dim3(BB), 512, SMEM_BYTES, stream>>>(Wh, bh, h0, out);
}